// Round 5
// baseline (8397.023 us; speedup 1.0000x reference)
//
#include <hip/hip_runtime.h>
#include <hip/hip_bf16.h>

#define BATCH  32
#define SEQ    1024
#define DMODEL 384
#define DINNER 768
#define DSTATE 16
#define DTRANK 24
#define NTOK   (BATCH * SEQ)   // 32768

typedef __hip_bfloat16 bf16;

__device__ __forceinline__ float b2f(bf16 v) { return __bfloat162float(v); }
__device__ __forceinline__ bf16  f2b(float v) { return __float2bfloat16(v); }

// Dual-dtype input load: inputs are either f32 or bf16; decided at runtime.
__device__ __forceinline__ float ldx(const void* p, size_t i, bool f32m) {
    return f32m ? ((const float*)p)[i] : b2f(((const bf16*)p)[i]);
}

// ------------------------------------------------------------------
// Input-dtype detection. If x is f32, its low mantissa halfwords are
// ~uniform random -> some decode as bf16 with exponent >= 0xE0 (|v|>=2^97),
// which never occurs in legit N(0,1)-scale bf16 data. Writes flag=1 (f32).
// ------------------------------------------------------------------
__global__ void detect_kernel(const unsigned short* __restrict__ x, int* flag) {
    int bad = 0;
    for (int i = threadIdx.x; i < 16384; i += 256) {
        int e = (x[i] >> 7) & 0xFF;
        bad |= (e >= 0xE0);
    }
    if (bad) atomicOr(flag, 1);
}

// ------------------------------------------------------------------
// Convert all weight tensors to canonical f32 in ws (exact for both dtypes).
// ------------------------------------------------------------------
struct CvtPack {
    const void* src[22];
    float*      dst[22];
    int         n[22];
};
__global__ void convert_kernel(CvtPack p, const int* __restrict__ flag) {
    bool f32m = (*flag != 0);
    int y = blockIdx.y;
    const void* s = p.src[y];
    float* d = p.dst[y];
    int n = p.n[y];
    for (int i = blockIdx.x * 256 + threadIdx.x; i < n; i += gridDim.x * 256)
        d[i] = ldx(s, i, f32m);
}

// ------------------------------------------------------------------
// LayerNorm: one wave per row of 384, 4 rows per 256-thread block.
// Reads external x (dual dtype), writes f32 xn.
// ------------------------------------------------------------------
__global__ void ln_kernel(const void* __restrict__ x, size_t xoff,
                          const float* __restrict__ gamma, const float* __restrict__ beta,
                          float* __restrict__ xn, const int* __restrict__ flag) {
    bool f32m = (*flag != 0);
    int wave = threadIdx.x >> 6;
    int lane = threadIdx.x & 63;
    int row  = blockIdx.x * 4 + wave;
    size_t base = xoff + (size_t)row * DMODEL;
    float v[6];
    float s = 0.f, s2 = 0.f;
#pragma unroll
    for (int i = 0; i < 6; ++i) {
        v[i] = ldx(x, base + lane + i * 64, f32m);
        s += v[i];
        s2 += v[i] * v[i];
    }
#pragma unroll
    for (int off = 32; off >= 1; off >>= 1) {
        s  += __shfl_down(s, off, 64);
        s2 += __shfl_down(s2, off, 64);
    }
    s  = __shfl(s, 0, 64);
    s2 = __shfl(s2, 0, 64);
    float mu   = s / DMODEL;
    float var  = s2 / DMODEL - mu * mu;
    float rstd = rsqrtf(var + 1e-5f);
    float* xnr = xn + (size_t)row * DMODEL;
#pragma unroll
    for (int i = 0; i < 6; ++i)
        xnr[lane + i * 64] = (v[i] - mu) * rstd * gamma[lane + i * 64] + beta[lane + i * 64];
}

// ------------------------------------------------------------------
// Tiled GEMM: C[M,N] = A[M,K] * W[N,K]^T  (all f32)
// 64x64 tile, BK=16, 256 threads, 4x4 per thread.
// ------------------------------------------------------------------
__global__ void gemm_kernel(const float* __restrict__ A, const float* __restrict__ W,
                            float* __restrict__ C, int M, int N, int K) {
    __shared__ float As[16][65];  // [kk][m]
    __shared__ float Bs[16][65];  // [kk][n]
    int tid = threadIdx.x;
    int tx = tid & 15, ty = tid >> 4;
    int m0 = blockIdx.y * 64, n0 = blockIdx.x * 64;
    int arow = tid >> 2;         // 0..63
    int acol = (tid & 3) * 4;    // 0,4,8,12
    float acc[4][4] = {};

    for (int k0 = 0; k0 < K; k0 += 16) {
        {
            const float* ap = A + (size_t)(m0 + arow) * K + k0 + acol;
#pragma unroll
            for (int i = 0; i < 4; ++i)
                As[acol + i][arow] = (k0 + acol + i < K) ? ap[i] : 0.f;
            int n = n0 + arow;
            const float* wp = W + (size_t)n * K + k0 + acol;
#pragma unroll
            for (int i = 0; i < 4; ++i)
                Bs[acol + i][arow] = (n < N && (k0 + acol + i < K)) ? wp[i] : 0.f;
        }
        __syncthreads();
#pragma unroll
        for (int kk = 0; kk < 16; ++kk) {
            float a[4], b[4];
#pragma unroll
            for (int i = 0; i < 4; ++i) a[i] = As[kk][ty * 4 + i];
#pragma unroll
            for (int j = 0; j < 4; ++j) b[j] = Bs[kk][tx * 4 + j];
#pragma unroll
            for (int i = 0; i < 4; ++i)
#pragma unroll
                for (int j = 0; j < 4; ++j) acc[i][j] += a[i] * b[j];
        }
        __syncthreads();
    }
#pragma unroll
    for (int i = 0; i < 4; ++i) {
        int m = m0 + ty * 4 + i;
        if (m >= M) continue;
#pragma unroll
        for (int j = 0; j < 4; ++j) {
            int n = n0 + tx * 4 + j;
            if (n < N) C[(size_t)m * N + n] = acc[i][j];
        }
    }
}

// ------------------------------------------------------------------
// Depthwise causal conv (fwd) / anti-causal reversed-tap conv (bwd) + SiLU.
// xi[T,768] -> xc[T,768], f32.
// ------------------------------------------------------------------
__global__ void conv_kernel(const float* __restrict__ xi_buf, const float* __restrict__ cw,
                            const float* __restrict__ cb, float* __restrict__ xc, int reverse) {
    int g = blockIdx.x * blockDim.x + threadIdx.x;
    int c  = g % DINNER;
    int bl = g / DINNER;
    int l = bl % SEQ;
    int b = bl / SEQ;
    float w[4];
#pragma unroll
    for (int k = 0; k < 4; ++k) w[k] = cw[c * 4 + k];
    const float* xi = xi_buf + (size_t)b * SEQ * DINNER + c;
    float acc = cb[c];
    if (!reverse) {
#pragma unroll
        for (int k = 0; k < 4; ++k) {
            int ll = l - 3 + k;
            if (ll >= 0) acc += xi[(size_t)ll * DINNER] * w[k];
        }
    } else {
#pragma unroll
        for (int j = 0; j < 4; ++j) {
            int ll = l + j;
            if (ll < SEQ) acc += xi[(size_t)ll * DINNER] * w[3 - j];
        }
    }
    xc[(size_t)bl * DINNER + c] = acc / (1.f + __expf(-acc));
}

// ------------------------------------------------------------------
// Selective scan (f32). One block = one chunk-local batch x 128 channels.
// Fuses dt projection (softplus), D-skip, silu(z) gating.
// ------------------------------------------------------------------
#define TSTEP 16
__global__ void scan_kernel(const float* __restrict__ xp, const float* __restrict__ xc,
                            const float* __restrict__ zb, const float* __restrict__ dtw_g,
                            const float* __restrict__ dtb_g, const float* __restrict__ Alog,
                            const float* __restrict__ Dg, float* __restrict__ ydir, int reverse) {
    __shared__ float xps[TSTEP][56];
    int b = blockIdx.x / 6;
    int chunk = blockIdx.x % 6;
    int c = chunk * 128 + threadIdx.x;

    float dtw[DTRANK];
#pragma unroll
    for (int r = 0; r < DTRANK; ++r) dtw[r] = dtw_g[c * DTRANK + r];
    float dtb = dtb_g[c];
    float Av[DSTATE];
#pragma unroll
    for (int n = 0; n < DSTATE; ++n) Av[n] = -__expf(Alog[c * DSTATE + n]);
    float Dv = Dg[c];
    float h[DSTATE];
#pragma unroll
    for (int n = 0; n < DSTATE; ++n) h[n] = 0.f;

    const size_t brow = (size_t)b * SEQ;
    for (int g0 = 0; g0 < SEQ; g0 += TSTEP) {
        __syncthreads();
        for (int i = threadIdx.x; i < TSTEP * 56; i += 128) {
            int s = i / 56, r = i % 56;
            int t = g0 + s;
            int tr = reverse ? (SEQ - 1 - t) : t;
            xps[s][r] = xp[(brow + tr) * 56 + r];
        }
        __syncthreads();
        for (int s = 0; s < TSTEP; ++s) {
            int t = g0 + s;
            int tr = reverse ? (SEQ - 1 - t) : t;
            size_t row = brow + tr;
            float dt = dtb;
#pragma unroll
            for (int r = 0; r < DTRANK; ++r) dt += xps[s][r] * dtw[r];
            dt = fmaxf(dt, 0.f) + log1pf(__expf(-fabsf(dt)));  // softplus
            float xcv = xc[row * DINNER + c];
            float zv  = zb[row * DINNER + c];
            float dtx = dt * xcv;
            float acc = 0.f;
#pragma unroll
            for (int n = 0; n < DSTATE; ++n) {
                float dA = __expf(dt * Av[n]);
                h[n] = dA * h[n] + dtx * xps[s][24 + n];
                acc += h[n] * xps[s][40 + n];
            }
            float yv = acc + xcv * Dv;
            yv *= zv / (1.f + __expf(-zv));  // * silu(z)
            ydir[row * DINNER + c] = yv;
        }
    }
}

// ------------------------------------------------------------------
// Gate GEMM + combine + residual. K=768 split: k<384 reads yf, else yb.
// out = sigmoid(acc+gb)*yf + (1-sig)*yb + x; dual-dtype x read & out store.
// ------------------------------------------------------------------
__global__ void gate_kernel(const float* __restrict__ yf, const float* __restrict__ yb,
                            const float* __restrict__ W, const float* __restrict__ gb,
                            const void* __restrict__ x, size_t xoff,
                            void* __restrict__ out, const int* __restrict__ flag) {
    __shared__ float As[16][65];
    __shared__ float Bs[16][65];
    bool f32m = (*flag != 0);
    int tid = threadIdx.x;
    int tx = tid & 15, ty = tid >> 4;
    int m0 = blockIdx.y * 64, n0 = blockIdx.x * 64;
    int arow = tid >> 2;
    int acol = (tid & 3) * 4;
    float acc[4][4] = {};

    for (int k0 = 0; k0 < 2 * DMODEL; k0 += 16) {
        const float* asrc = (k0 < DMODEL) ? yf : yb;
        int kbase = (k0 < DMODEL) ? k0 : k0 - DMODEL;
        const float* ap = asrc + (size_t)(m0 + arow) * DMODEL + kbase + acol;
#pragma unroll
        for (int i = 0; i < 4; ++i) As[acol + i][arow] = ap[i];
        const float* wp = W + (size_t)(n0 + arow) * (2 * DMODEL) + k0 + acol;
#pragma unroll
        for (int i = 0; i < 4; ++i) Bs[acol + i][arow] = wp[i];
        __syncthreads();
#pragma unroll
        for (int kk = 0; kk < 16; ++kk) {
            float a[4], b[4];
#pragma unroll
            for (int i = 0; i < 4; ++i) a[i] = As[kk][ty * 4 + i];
#pragma unroll
            for (int j = 0; j < 4; ++j) b[j] = Bs[kk][tx * 4 + j];
#pragma unroll
            for (int i = 0; i < 4; ++i)
#pragma unroll
                for (int j = 0; j < 4; ++j) acc[i][j] += a[i] * b[j];
        }
        __syncthreads();
    }
#pragma unroll
    for (int i = 0; i < 4; ++i) {
        int m = m0 + ty * 4 + i;
#pragma unroll
        for (int j = 0; j < 4; ++j) {
            int n = n0 + tx * 4 + j;
            float g = 1.f / (1.f + __expf(-(acc[i][j] + gb[n])));
            float yfv = yf[(size_t)m * DMODEL + n];
            float ybv = yb[(size_t)m * DMODEL + n];
            size_t gi = xoff + (size_t)m * DMODEL + n;
            float xv = ldx(x, gi, f32m);
            float r = g * yfv + (1.f - g) * ybv + xv;
            if (f32m) ((float*)out)[gi] = r;
            else      ((bf16*)out)[gi] = f2b(r);
        }
    }
}

// ------------------------------------------------------------------
extern "C" void kernel_launch(void* const* d_in, const int* in_sizes, int n_in,
                              void* d_out, int out_size, void* d_ws, size_t ws_size,
                              hipStream_t stream) {
    (void)n_in; (void)out_size;

    // Input-order detection, robust to order AND size-units AND dtype:
    //   dict order:      in_sizes[4]=gate_b   -> 384 el / 768 B(bf16) / 1536 B(f32)
    //   signature order: in_sizes[4]=f_conv_w -> 3072 el / 6144 B / 12288 B
    bool dict_order = (in_sizes[4] < 2048);
    int fbase = dict_order ? 5 : 3;
    int bbase = dict_order ? 14 : 12;
    int gwi = dict_order ? 3 : 21;
    int gbi = dict_order ? 4 : 22;

    auto al = [](size_t b) { return (b + 255) & ~(size_t)255; };
    char* ws = (char*)d_ws;
    size_t off = 0;
    auto alloc = [&](size_t bytes) {
        void* p = ws + off;
        off += al(bytes);
        return p;
    };

    int* flag = (int*)alloc(256);

    // --- converted f32 weights ---
    CvtPack pk{};
    int cnt = 0;
    auto add = [&](int idx, int n) {
        float* d = (float*)alloc((size_t)n * 4);
        pk.src[cnt] = d_in[idx];
        pk.dst[cnt] = d;
        pk.n[cnt] = n;
        ++cnt;
        return d;
    };
    float* ln_gc = add(1, DMODEL);
    float* ln_bc = add(2, DMODEL);
    float* gate_wc = add(gwi, DMODEL * 2 * DMODEL);
    float* gate_bc = add(gbi, DMODEL);
    static const int dsz[9] = { 2 * DINNER * DMODEL, DINNER * 4, DINNER,
                                (DTRANK + 2 * DSTATE) * DINNER, DINNER * DTRANK, DINNER,
                                DINNER * DSTATE, DINNER, DMODEL * DINNER };
    float* wdir[2][9];
    for (int d = 0; d < 2; ++d) {
        int base = d ? bbase : fbase;
        for (int j = 0; j < 9; ++j) wdir[d][j] = add(base + j, dsz[j]);
    }
    size_t fixed = off;

    // --- chunk sizing (f32 intermediates) ---
    auto chunk_need = [&](int bc) {
        size_t T = (size_t)bc * SEQ;
        return al(T * DMODEL * 4)         // xn
             + 3 * al(T * DINNER * 4)     // xi(/ydir), z, xc
             + al(T * 56 * 4)             // xp
             + 2 * al(T * DMODEL * 4);    // yf_c, yb_c
    };
    int Bc = 32;
    while (Bc > 1 && fixed + chunk_need(Bc) > ws_size) Bc >>= 1;
    size_t T = (size_t)Bc * SEQ;

    float* xn_c = (float*)alloc(T * DMODEL * 4);
    float* xib  = (float*)alloc(T * DINNER * 4);   // xi; reused as ydir after conv
    float* zb   = (float*)alloc(T * DINNER * 4);
    float* xcb  = (float*)alloc(T * DINNER * 4);
    float* xpb  = (float*)alloc(T * 56 * 4);
    float* yf_c = (float*)alloc(T * DMODEL * 4);
    float* yb_c = (float*)alloc(T * DMODEL * 4);
    float* ydir = xib;  // alias: xi dead after conv_kernel

    hipMemsetAsync(flag, 0, 4, stream);
    detect_kernel<<<1, 256, 0, stream>>>((const unsigned short*)d_in[0], flag);
    convert_kernel<<<dim3(32, 22), 256, 0, stream>>>(pk, flag);

    for (int c0 = 0; c0 < BATCH; c0 += Bc) {
        size_t tok0 = (size_t)c0 * SEQ;

        ln_kernel<<<(unsigned)(T / 4), 256, 0, stream>>>(
            d_in[0], tok0 * DMODEL, ln_gc, ln_bc, xn_c, flag);

        for (int dir = 0; dir < 2; ++dir) {
            float* in_w    = wdir[dir][0];
            float* conv_w  = wdir[dir][1];
            float* conv_b  = wdir[dir][2];
            float* xproj_w = wdir[dir][3];
            float* dt_w    = wdir[dir][4];
            float* dt_b    = wdir[dir][5];
            float* A_log   = wdir[dir][6];
            float* Dp      = wdir[dir][7];
            float* out_w   = wdir[dir][8];

            gemm_kernel<<<dim3(DINNER / 64, T / 64), 256, 0, stream>>>(
                xn_c, in_w, xib, (int)T, DINNER, DMODEL);
            gemm_kernel<<<dim3(DINNER / 64, T / 64), 256, 0, stream>>>(
                xn_c, in_w + (size_t)DINNER * DMODEL, zb, (int)T, DINNER, DMODEL);
            conv_kernel<<<(unsigned)((T * DINNER) / 256), 256, 0, stream>>>(
                xib, conv_w, conv_b, xcb, dir);
            gemm_kernel<<<dim3(1, T / 64), 256, 0, stream>>>(
                xcb, xproj_w, xpb, (int)T, 56, DINNER);
            scan_kernel<<<Bc * 6, 128, 0, stream>>>(
                xpb, xcb, zb, dt_w, dt_b, A_log, Dp, ydir, dir);
            gemm_kernel<<<dim3(DMODEL / 64, T / 64), 256, 0, stream>>>(
                ydir, out_w, dir ? yb_c : yf_c, (int)T, DMODEL, DINNER);
        }

        gate_kernel<<<dim3(DMODEL / 64, T / 64), 256, 0, stream>>>(
            yf_c, yb_c, gate_wc, gate_bc, d_in[0], tok0 * DMODEL, d_out, flag);
    }
}

// Round 6
// 1762.059 us; speedup vs baseline: 4.7655x; 4.7655x over previous
//
#include <hip/hip_runtime.h>
#include <hip/hip_bf16.h>

#define BATCH  32
#define SEQ    1024
#define DMODEL 384
#define DINNER 768
#define DSTATE 16
#define DTRANK 24
#define NTOK   (BATCH * SEQ)
#define TC     8              // time chunks for parallel scan
#define CL     (SEQ / TC)     // 128 steps per chunk

typedef __hip_bfloat16 bf16;
typedef __attribute__((ext_vector_type(8))) short frag_ab;  // 8 bf16
typedef __attribute__((ext_vector_type(4))) float frag_cd;  // 4 f32

__device__ __forceinline__ float b2f(bf16 v) { return __bfloat162float(v); }
__device__ __forceinline__ bf16  f2b(float v) { return __float2bfloat16(v); }
__device__ __forceinline__ float ldx(const void* p, size_t i, bool f32m) {
    return f32m ? ((const float*)p)[i] : b2f(((const bf16*)p)[i]);
}

// ------------------------------------------------------------------
// Input-dtype detection (f32 vs bf16), as verified in R5 (inputs are f32).
// ------------------------------------------------------------------
__global__ void detect_kernel(const unsigned short* __restrict__ x, int* flag) {
    int bad = 0;
    for (int i = threadIdx.x; i < 16384; i += 256) {
        int e = (x[i] >> 7) & 0xFF;
        bad |= (e >= 0xE0);
    }
    if (bad) atomicOr(flag, 1);
}

// ------------------------------------------------------------------
// Weight conversion: small params -> f32, GEMM weights -> bf16.
// ------------------------------------------------------------------
struct CvtF { const void* src[15]; float* dst[15]; int n[15]; };
struct CvtB { const void* src[7];  bf16*  dst[7];  int n[7];  };

__global__ void convert_f_kernel(CvtF p, const int* __restrict__ flag) {
    bool f32m = (*flag != 0);
    int y = blockIdx.y;
    const void* s = p.src[y];
    float* d = p.dst[y];
    int n = p.n[y];
    for (int i = blockIdx.x * 256 + threadIdx.x; i < n; i += gridDim.x * 256)
        d[i] = ldx(s, i, f32m);
}
__global__ void convert_b_kernel(CvtB p, const int* __restrict__ flag) {
    bool f32m = (*flag != 0);
    int y = blockIdx.y;
    const void* s = p.src[y];
    bf16* d = p.dst[y];
    int n = p.n[y];
    for (int i = blockIdx.x * 256 + threadIdx.x; i < n; i += gridDim.x * 256)
        d[i] = f2b(ldx(s, i, f32m));
}

// ------------------------------------------------------------------
// LayerNorm: one wave per row of 384; writes bf16 xn.
// ------------------------------------------------------------------
__global__ void ln_kernel(const void* __restrict__ x, size_t xoff,
                          const float* __restrict__ gamma, const float* __restrict__ beta,
                          bf16* __restrict__ xn, const int* __restrict__ flag) {
    bool f32m = (*flag != 0);
    int wave = threadIdx.x >> 6;
    int lane = threadIdx.x & 63;
    int row  = blockIdx.x * 4 + wave;
    size_t base = xoff + (size_t)row * DMODEL;
    float v[6];
    float s = 0.f, s2 = 0.f;
#pragma unroll
    for (int i = 0; i < 6; ++i) {
        v[i] = ldx(x, base + lane + i * 64, f32m);
        s += v[i];
        s2 += v[i] * v[i];
    }
#pragma unroll
    for (int off = 32; off >= 1; off >>= 1) {
        s  += __shfl_down(s, off, 64);
        s2 += __shfl_down(s2, off, 64);
    }
    s  = __shfl(s, 0, 64);
    s2 = __shfl(s2, 0, 64);
    float mu   = s / DMODEL;
    float var  = s2 / DMODEL - mu * mu;
    float rstd = rsqrtf(var + 1e-5f);
    bf16* xnr = xn + (size_t)row * DMODEL;
#pragma unroll
    for (int i = 0; i < 6; ++i)
        xnr[lane + i * 64] = f2b((v[i] - mu) * rstd * gamma[lane + i * 64] + beta[lane + i * 64]);
}

// ------------------------------------------------------------------
// MFMA bf16 GEMM, 128x128 tile, BK=32, 256 threads (4 waves, 2x2 of 64x64).
// C[M,N] = A[M,K] @ W[N,K]^T.  M,N multiples of 128 (xp mode: W zero-padded).
// MODE 0: bf16 store to C (ldc, cofs).  MODE 1: gate epilogue.
// MODE 2: f32 store to Cf, 56 cols.
// Fragment layouts per guide (m89/m91-verified):
//   A/B: [idx=lane&15][k=(lane>>4)*8+j]; C/D: col=lane&15, row=(lane>>4)*4+reg.
// ------------------------------------------------------------------
template <int MODE>
__global__ __launch_bounds__(256) void gemm_mfma(
    const bf16* __restrict__ A, const bf16* __restrict__ W,
    int K, int lda, int ldw,
    bf16* __restrict__ C, int ldc, int cofs,
    float* __restrict__ Cf,
    const float* __restrict__ gb, const void* __restrict__ xg, size_t xoff,
    void* __restrict__ outg, const int* __restrict__ flag) {
    __shared__ bf16 Als[128][32];
    __shared__ bf16 Bls[128][32];
    int tid = threadIdx.x;
    int lane = tid & 63;
    int w = tid >> 6;
    int wm = w & 1, wn = w >> 1;
    int m0 = blockIdx.y * 128, n0 = blockIdx.x * 128;
    int row = tid >> 2, kc = tid & 3;
    int mr = lane & 15, quad = lane >> 4;

    frag_cd acc[4][4] = {};

    for (int k0 = 0; k0 < K; k0 += 32) {
        uint4 a0 = *(const uint4*)(A + (size_t)(m0 + row) * lda + k0 + kc * 8);
        uint4 a1 = *(const uint4*)(A + (size_t)(m0 + 64 + row) * lda + k0 + kc * 8);
        uint4 b0 = *(const uint4*)(W + (size_t)(n0 + row) * ldw + k0 + kc * 8);
        uint4 b1 = *(const uint4*)(W + (size_t)(n0 + 64 + row) * ldw + k0 + kc * 8);
        __syncthreads();   // prior iteration's LDS reads done
        *(uint4*)&Als[row][kc * 8]      = a0;
        *(uint4*)&Als[64 + row][kc * 8] = a1;
        *(uint4*)&Bls[row][kc * 8]      = b0;
        *(uint4*)&Bls[64 + row][kc * 8] = b1;
        __syncthreads();
        frag_ab af[4], bfr[4];
#pragma unroll
        for (int r = 0; r < 4; ++r)
            af[r] = *(const frag_ab*)&Als[wm * 64 + r * 16 + mr][quad * 8];
#pragma unroll
        for (int c = 0; c < 4; ++c)
            bfr[c] = *(const frag_ab*)&Bls[wn * 64 + c * 16 + mr][quad * 8];
#pragma unroll
        for (int r = 0; r < 4; ++r)
#pragma unroll
            for (int c = 0; c < 4; ++c)
                acc[r][c] = __builtin_amdgcn_mfma_f32_16x16x32_bf16(af[r], bfr[c], acc[r][c], 0, 0, 0);
    }

    bool f32m = (MODE == 1) ? (*flag != 0) : false;
#pragma unroll
    for (int r = 0; r < 4; ++r) {
#pragma unroll
        for (int c = 0; c < 4; ++c) {
#pragma unroll
            for (int reg = 0; reg < 4; ++reg) {
                int gm = m0 + wm * 64 + r * 16 + quad * 4 + reg;
                int gn = n0 + wn * 64 + c * 16 + mr;
                float v = acc[r][c][reg];
                if (MODE == 0) {
                    C[(size_t)gm * ldc + cofs + gn] = f2b(v);
                } else if (MODE == 2) {
                    if (gn < DTRANK + 2 * DSTATE) Cf[(size_t)gm * 56 + gn] = v;
                } else {  // gate: g*yf + (1-g)*yb + x  (A == ycat)
                    float g   = 1.f / (1.f + __expf(-(v + gb[gn])));
                    float yfv = b2f(A[(size_t)gm * DINNER + gn]);
                    float ybv = b2f(A[(size_t)gm * DINNER + DMODEL + gn]);
                    size_t gi = xoff + (size_t)gm * DMODEL + gn;
                    float xv  = f32m ? ((const float*)xg)[gi] : b2f(((const bf16*)xg)[gi]);
                    float rr  = g * yfv + (1.f - g) * ybv + xv;
                    if (f32m) ((float*)outg)[gi] = rr;
                    else      ((bf16*)outg)[gi]  = f2b(rr);
                }
            }
        }
    }
}

// ------------------------------------------------------------------
// Depthwise conv (causal fwd / anti-causal reversed-tap bwd) + SiLU, bf16.
// ------------------------------------------------------------------
__global__ void conv_kernel(const bf16* __restrict__ xi_buf, const float* __restrict__ cw,
                            const float* __restrict__ cb, bf16* __restrict__ xc, int reverse) {
    int g = blockIdx.x * blockDim.x + threadIdx.x;
    int c  = g % DINNER;
    int bl = g / DINNER;
    int l = bl % SEQ;
    int b = bl / SEQ;
    float w[4];
#pragma unroll
    for (int k = 0; k < 4; ++k) w[k] = cw[c * 4 + k];
    const bf16* xi = xi_buf + (size_t)b * SEQ * DINNER + c;
    float acc = cb[c];
    if (!reverse) {
#pragma unroll
        for (int k = 0; k < 4; ++k) {
            int ll = l - 3 + k;
            if (ll >= 0) acc += b2f(xi[(size_t)ll * DINNER]) * w[k];
        }
    } else {
#pragma unroll
        for (int j = 0; j < 4; ++j) {
            int ll = l + j;
            if (ll < SEQ) acc += b2f(xi[(size_t)ll * DINNER]) * w[3 - j];
        }
    }
    xc[(size_t)bl * DINNER + c] = f2b(acc / (1.f + __expf(-acc)));
}

// ------------------------------------------------------------------
// Chunked selective scan. h[t] = dA[t] h[t-1] + (dt x)[t] B[t] is diagonal-
// linear -> split SEQ into TC chunks.
// PHASE 0: per chunk, from h=0: P = prod dA, hend; store {P, hend}.
// stitch : serial compose over tc; stores h_in into the P slot.
// PHASE 1: re-run from h_in, emit y (fused D-skip + silu(z) gate).
// states layout: [bidx][j 0..31][tid] f32, coalesced over tid.
// ------------------------------------------------------------------
template <int PHASE>
__global__ void scan_phase(const float* __restrict__ xp, const bf16* __restrict__ xc,
                           const bf16* __restrict__ zb, const float* __restrict__ dtw_g,
                           const float* __restrict__ dtb_g, const float* __restrict__ Alog,
                           const float* __restrict__ Dg, float* __restrict__ states,
                           bf16* __restrict__ ydir, int reverse) {
    __shared__ float xps[16][56];
    int tid = threadIdx.x;
    int bidx = blockIdx.x;
    int tc  = bidx % TC;
    int cgb = bidx / TC;       // bb*6+cg
    int cg  = cgb % 6;
    int bb  = cgb / 6;
    int c = cg * 128 + tid;

    float dtw[DTRANK];
#pragma unroll
    for (int r = 0; r < DTRANK; ++r) dtw[r] = dtw_g[c * DTRANK + r];
    float dtb = dtb_g[c];
    float Av[DSTATE];
#pragma unroll
    for (int n = 0; n < DSTATE; ++n) Av[n] = -__expf(Alog[c * DSTATE + n]);
    float Dv = Dg[c];

    float h[DSTATE], P[DSTATE];
    size_t sbase = (size_t)bidx * 32;
    if (PHASE == 0) {
#pragma unroll
        for (int n = 0; n < DSTATE; ++n) { h[n] = 0.f; P[n] = 1.f; }
    } else {
#pragma unroll
        for (int n = 0; n < DSTATE; ++n) h[n] = states[(sbase + n) * 128 + tid];
    }

    const size_t brow = (size_t)bb * SEQ;
    for (int g0 = tc * CL; g0 < tc * CL + CL; g0 += 16) {
        __syncthreads();
        for (int i = tid; i < 16 * 56; i += 128) {
            int s = i / 56, r = i % 56;
            int t = g0 + s;
            int tr = reverse ? (SEQ - 1 - t) : t;
            xps[s][r] = xp[(brow + tr) * 56 + r];
        }
        __syncthreads();
        for (int s = 0; s < 16; ++s) {
            int t = g0 + s;
            int tr = reverse ? (SEQ - 1 - t) : t;
            size_t row = brow + tr;
            float dt = dtb;
#pragma unroll
            for (int r = 0; r < DTRANK; ++r) dt += xps[s][r] * dtw[r];
            dt = fmaxf(dt, 0.f) + log1pf(__expf(-fabsf(dt)));  // softplus
            float xcv = b2f(xc[row * DINNER + c]);
            float dtx = dt * xcv;
            if (PHASE == 0) {
#pragma unroll
                for (int n = 0; n < DSTATE; ++n) {
                    float dA = __expf(dt * Av[n]);
                    h[n] = dA * h[n] + dtx * xps[s][24 + n];
                    P[n] *= dA;
                }
            } else {
                float zv = b2f(zb[row * DINNER + c]);
                float accv = 0.f;
#pragma unroll
                for (int n = 0; n < DSTATE; ++n) {
                    float dA = __expf(dt * Av[n]);
                    h[n] = dA * h[n] + dtx * xps[s][24 + n];
                    accv += h[n] * xps[s][40 + n];
                }
                float yv = accv + xcv * Dv;
                yv *= zv / (1.f + __expf(-zv));
                ydir[row * DINNER + c] = f2b(yv);
            }
        }
    }
    if (PHASE == 0) {
#pragma unroll
        for (int n = 0; n < DSTATE; ++n) {
            states[(sbase + n) * 128 + tid]      = P[n];
            states[(sbase + 16 + n) * 128 + tid] = h[n];
        }
    }
}

__global__ void scan_stitch(float* __restrict__ states) {
    int tid = threadIdx.x;
    int cgb = blockIdx.x;
    float h[DSTATE];
#pragma unroll
    for (int n = 0; n < DSTATE; ++n) h[n] = 0.f;
    for (int tc = 0; tc < TC; ++tc) {
        size_t base = ((size_t)cgb * TC + tc) * 32;
#pragma unroll
        for (int n = 0; n < DSTATE; ++n) {
            float Pv = states[(base + n) * 128 + tid];
            float ev = states[(base + 16 + n) * 128 + tid];
            states[(base + n) * 128 + tid] = h[n];   // h_in for this chunk
            h[n] = Pv * h[n] + ev;
        }
    }
}

// ------------------------------------------------------------------
extern "C" void kernel_launch(void* const* d_in, const int* in_sizes, int n_in,
                              void* d_out, int out_size, void* d_ws, size_t ws_size,
                              hipStream_t stream) {
    (void)n_in; (void)out_size;
    bool dict_order = (in_sizes[4] < 2048);
    int fbase = dict_order ? 5 : 3;
    int bbase = dict_order ? 14 : 12;
    int gwi = dict_order ? 3 : 21;
    int gbi = dict_order ? 4 : 22;

    auto al = [](size_t b) { return (b + 255) & ~(size_t)255; };
    char* ws = (char*)d_ws;
    size_t off = 0;
    auto alloc = [&](size_t bytes) {
        void* p = ws + off;
        off += al(bytes);
        return p;
    };

    int* flag = (int*)alloc(256);

    // f32 small params
    CvtF pf{};
    int cf = 0;
    auto addf = [&](int idx, int n) {
        float* d = (float*)alloc((size_t)n * 4);
        pf.src[cf] = d_in[idx]; pf.dst[cf] = d; pf.n[cf] = n; ++cf;
        return d;
    };
    float* ln_gc   = addf(1, DMODEL);
    float* ln_bc   = addf(2, DMODEL);
    float* gate_bc = addf(gbi, DMODEL);
    float* convw_f[2], *convb_f[2], *dtw_f[2], *dtb_f[2], *alog_f[2], *dd_f[2];
    for (int d = 0; d < 2; ++d) {
        int base = d ? bbase : fbase;
        convw_f[d] = addf(base + 1, DINNER * 4);
        convb_f[d] = addf(base + 2, DINNER);
        dtw_f[d]   = addf(base + 4, DINNER * DTRANK);
        dtb_f[d]   = addf(base + 5, DINNER);
        alog_f[d]  = addf(base + 6, DINNER * DSTATE);
        dd_f[d]    = addf(base + 7, DINNER);
    }

    // bf16 GEMM weights (xproj zero-padded to 128 rows)
    CvtB pb{};
    int cb = 0;
    auto addb = [&](int idx, int n, size_t alloc_n) {
        bf16* d = (bf16*)alloc(alloc_n * 2);
        pb.src[cb] = d_in[idx]; pb.dst[cb] = d; pb.n[cb] = n; ++cb;
        return d;
    };
    bf16* gate_wb = addb(gwi, DMODEL * 2 * DMODEL, (size_t)DMODEL * 2 * DMODEL);
    bf16 *inw_b[2], *xpw_b[2], *outw_b[2];
    for (int d = 0; d < 2; ++d) {
        int base = d ? bbase : fbase;
        inw_b[d]  = addb(base + 0, 2 * DINNER * DMODEL, (size_t)2 * DINNER * DMODEL);
        xpw_b[d]  = addb(base + 3, 56 * DINNER, (size_t)128 * DINNER);  // padded
        outw_b[d] = addb(base + 8, DMODEL * DINNER, (size_t)DMODEL * DINNER);
    }
    size_t fixed = off;

    // chunk buffers (bf16 activations)
    auto chunk_need = [&](int bc) {
        size_t T = (size_t)bc * SEQ;
        return al(T * DMODEL * 2)               // xn
             + 3 * al(T * DINNER * 2)           // xi(/ydir), z, xc
             + al(T * 56 * 4)                   // xp f32
             + al(T * DINNER * 2)               // ycat
             + al((size_t)bc * 6 * TC * 32 * 128 * 4);  // scan states
    };
    int Bc = 32;
    while (Bc > 1 && fixed + chunk_need(Bc) > ws_size) Bc >>= 1;
    size_t T = (size_t)Bc * SEQ;

    bf16*  xn_c   = (bf16*)alloc(T * DMODEL * 2);
    bf16*  xib    = (bf16*)alloc(T * DINNER * 2);
    bf16*  zb     = (bf16*)alloc(T * DINNER * 2);
    bf16*  xcb    = (bf16*)alloc(T * DINNER * 2);
    float* xpb    = (float*)alloc(T * 56 * 4);
    bf16*  ycat   = (bf16*)alloc(T * DINNER * 2);
    float* states = (float*)alloc((size_t)Bc * 6 * TC * 32 * 128 * 4);
    bf16*  ydir   = xib;  // alias: xi dead after conv

    hipMemsetAsync(flag, 0, 4, stream);
    for (int d = 0; d < 2; ++d)
        hipMemsetAsync(xpw_b[d], 0, (size_t)128 * DINNER * 2, stream);
    detect_kernel<<<1, 256, 0, stream>>>((const unsigned short*)d_in[0], flag);
    convert_f_kernel<<<dim3(8, 15), 256, 0, stream>>>(pf, flag);
    convert_b_kernel<<<dim3(32, 7), 256, 0, stream>>>(pb, flag);

    for (int c0 = 0; c0 < BATCH; c0 += Bc) {
        size_t tok0 = (size_t)c0 * SEQ;

        ln_kernel<<<(unsigned)(T / 4), 256, 0, stream>>>(
            d_in[0], tok0 * DMODEL, ln_gc, ln_bc, xn_c, flag);

        for (int dir = 0; dir < 2; ++dir) {
            // in-proj: xi and z halves
            gemm_mfma<0><<<dim3(DINNER / 128, T / 128), 256, 0, stream>>>(
                xn_c, inw_b[dir], DMODEL, DMODEL, DMODEL,
                xib, DINNER, 0, nullptr, nullptr, nullptr, 0, nullptr, flag);
            gemm_mfma<0><<<dim3(DINNER / 128, T / 128), 256, 0, stream>>>(
                xn_c, inw_b[dir] + (size_t)DINNER * DMODEL, DMODEL, DMODEL, DMODEL,
                zb, DINNER, 0, nullptr, nullptr, nullptr, 0, nullptr, flag);
            conv_kernel<<<(unsigned)((T * DINNER) / 256), 256, 0, stream>>>(
                xib, convw_f[dir], convb_f[dir], xcb, dir);
            // x-proj (N=56 padded to 128)
            gemm_mfma<2><<<dim3(1, T / 128), 256, 0, stream>>>(
                xcb, xpw_b[dir], DINNER, DINNER, DINNER,
                nullptr, 0, 0, xpb, nullptr, nullptr, 0, nullptr, flag);
            // chunked scan
            scan_phase<0><<<Bc * 6 * TC, 128, 0, stream>>>(
                xpb, xcb, zb, dtw_f[dir], dtb_f[dir], alog_f[dir], dd_f[dir],
                states, nullptr, dir);
            scan_stitch<<<Bc * 6, 128, 0, stream>>>(states);
            scan_phase<1><<<Bc * 6 * TC, 128, 0, stream>>>(
                xpb, xcb, zb, dtw_f[dir], dtb_f[dir], alog_f[dir], dd_f[dir],
                states, ydir, dir);
            // out-proj into ycat columns [dir*384, dir*384+384)
            gemm_mfma<0><<<dim3(DMODEL / 128, T / 128), 256, 0, stream>>>(
                ydir, outw_b[dir], DINNER, DINNER, DINNER,
                ycat, DINNER, dir * DMODEL, nullptr, nullptr, nullptr, 0, nullptr, flag);
        }

        // gate GEMM + combine + residual, fused epilogue
        gemm_mfma<1><<<dim3(DMODEL / 128, T / 128), 256, 0, stream>>>(
            ycat, gate_wb, DINNER, DINNER, DINNER,
            nullptr, 0, 0, nullptr, gate_bc, d_in[0], tok0 * DMODEL, d_out, flag);
    }
}

// Round 7
// 1617.455 us; speedup vs baseline: 5.1915x; 1.0894x over previous
//
#include <hip/hip_runtime.h>
#include <hip/hip_bf16.h>

#define BATCH  32
#define SEQ    1024
#define DMODEL 384
#define DINNER 768
#define DSTATE 16
#define DTRANK 24
#define NTOK   (BATCH * SEQ)
#define TC     32             // time chunks for parallel scan
#define CL     (SEQ / TC)     // 32 steps per chunk

typedef __hip_bfloat16 bf16;
typedef __attribute__((ext_vector_type(8))) short frag_ab;  // 8 bf16
typedef __attribute__((ext_vector_type(4))) float frag_cd;  // 4 f32

__device__ __forceinline__ float b2f(bf16 v) { return __bfloat162float(v); }
__device__ __forceinline__ bf16  f2b(float v) { return __float2bfloat16(v); }
__device__ __forceinline__ float ldx(const void* p, size_t i, bool f32m) {
    return f32m ? ((const float*)p)[i] : b2f(((const bf16*)p)[i]);
}

// ------------------------------------------------------------------
// Input-dtype detection (f32 vs bf16). Verified R5: inputs are f32.
// ------------------------------------------------------------------
__global__ void detect_kernel(const unsigned short* __restrict__ x, int* flag) {
    int bad = 0;
    for (int i = threadIdx.x; i < 16384; i += 256) {
        int e = (x[i] >> 7) & 0xFF;
        bad |= (e >= 0xE0);
    }
    if (bad) atomicOr(flag, 1);
}

// ------------------------------------------------------------------
// A-structure check: Av[n]/Av[0] == n+1 (A_log = log(1..16) broadcast).
// Sets flag[1]=1 if NOT structured -> scan uses generic 16-exp path.
// ------------------------------------------------------------------
__global__ void struct_check(const float* __restrict__ alog, int* flag) {
    int c = blockIdx.x * 256 + threadIdx.x;
    if (c >= DINNER) return;
    float a0 = __expf(alog[c * 16]);
    int bad = 0;
#pragma unroll
    for (int n = 1; n < DSTATE; ++n) {
        float r = __expf(alog[c * 16 + n]) / a0;
        bad |= (fabsf(r - (float)(n + 1)) > 1e-3f * (n + 1));
    }
    if (bad) atomicOr(flag + 1, 1);
}

// ------------------------------------------------------------------
// Weight conversion: small params -> f32, GEMM weights -> bf16.
// ------------------------------------------------------------------
struct CvtF { const void* src[15]; float* dst[15]; int n[15]; };
struct CvtB { const void* src[7];  bf16*  dst[7];  int n[7];  };

__global__ void convert_f_kernel(CvtF p, const int* __restrict__ flag) {
    bool f32m = (*flag != 0);
    int y = blockIdx.y;
    const void* s = p.src[y];
    float* d = p.dst[y];
    int n = p.n[y];
    for (int i = blockIdx.x * 256 + threadIdx.x; i < n; i += gridDim.x * 256)
        d[i] = ldx(s, i, f32m);
}
__global__ void convert_b_kernel(CvtB p, const int* __restrict__ flag) {
    bool f32m = (*flag != 0);
    int y = blockIdx.y;
    const void* s = p.src[y];
    bf16* d = p.dst[y];
    int n = p.n[y];
    for (int i = blockIdx.x * 256 + threadIdx.x; i < n; i += gridDim.x * 256)
        d[i] = f2b(ldx(s, i, f32m));
}

// ------------------------------------------------------------------
// LayerNorm: one wave per row of 384; writes bf16 xn.
// ------------------------------------------------------------------
__global__ void ln_kernel(const void* __restrict__ x, size_t xoff,
                          const float* __restrict__ gamma, const float* __restrict__ beta,
                          bf16* __restrict__ xn, const int* __restrict__ flag) {
    bool f32m = (*flag != 0);
    int wave = threadIdx.x >> 6;
    int lane = threadIdx.x & 63;
    int row  = blockIdx.x * 4 + wave;
    size_t base = xoff + (size_t)row * DMODEL;
    float v[6];
    float s = 0.f, s2 = 0.f;
#pragma unroll
    for (int i = 0; i < 6; ++i) {
        v[i] = ldx(x, base + lane + i * 64, f32m);
        s += v[i];
        s2 += v[i] * v[i];
    }
#pragma unroll
    for (int off = 32; off >= 1; off >>= 1) {
        s  += __shfl_down(s, off, 64);
        s2 += __shfl_down(s2, off, 64);
    }
    s  = __shfl(s, 0, 64);
    s2 = __shfl(s2, 0, 64);
    float mu   = s / DMODEL;
    float var  = s2 / DMODEL - mu * mu;
    float rstd = rsqrtf(var + 1e-5f);
    bf16* xnr = xn + (size_t)row * DMODEL;
#pragma unroll
    for (int i = 0; i < 6; ++i)
        xnr[lane + i * 64] = f2b((v[i] - mu) * rstd * gamma[lane + i * 64] + beta[lane + i * 64]);
}

// ------------------------------------------------------------------
// MFMA bf16 GEMM, 128x128 tile, BK=32, 256 threads (2x2 waves of 64x64).
// C[M,N] = A[M,K] @ W[N,K]^T.
// MODE 0: bf16 store (ldc, cofs).        MODE 1: gate epilogue -> d_out.
// MODE 2: f32 store, 56 valid cols.      MODE 3: z epilogue: C *= silu(v).
// ------------------------------------------------------------------
template <int MODE>
__global__ __launch_bounds__(256) void gemm_mfma(
    const bf16* __restrict__ A, const bf16* __restrict__ W,
    int K, int lda, int ldw,
    bf16* __restrict__ C, int ldc, int cofs,
    float* __restrict__ Cf,
    const float* __restrict__ gb, const void* __restrict__ xg, size_t xoff,
    void* __restrict__ outg, const int* __restrict__ flag) {
    __shared__ bf16 Als[128][32];
    __shared__ bf16 Bls[128][32];
    int tid = threadIdx.x;
    int lane = tid & 63;
    int w = tid >> 6;
    int wm = w & 1, wn = w >> 1;
    int m0 = blockIdx.y * 128, n0 = blockIdx.x * 128;
    int row = tid >> 2, kc = tid & 3;
    int mr = lane & 15, quad = lane >> 4;

    frag_cd acc[4][4] = {};

    for (int k0 = 0; k0 < K; k0 += 32) {
        uint4 a0 = *(const uint4*)(A + (size_t)(m0 + row) * lda + k0 + kc * 8);
        uint4 a1 = *(const uint4*)(A + (size_t)(m0 + 64 + row) * lda + k0 + kc * 8);
        uint4 b0 = *(const uint4*)(W + (size_t)(n0 + row) * ldw + k0 + kc * 8);
        uint4 b1 = *(const uint4*)(W + (size_t)(n0 + 64 + row) * ldw + k0 + kc * 8);
        __syncthreads();
        *(uint4*)&Als[row][kc * 8]      = a0;
        *(uint4*)&Als[64 + row][kc * 8] = a1;
        *(uint4*)&Bls[row][kc * 8]      = b0;
        *(uint4*)&Bls[64 + row][kc * 8] = b1;
        __syncthreads();
        frag_ab af[4], bfr[4];
#pragma unroll
        for (int r = 0; r < 4; ++r)
            af[r] = *(const frag_ab*)&Als[wm * 64 + r * 16 + mr][quad * 8];
#pragma unroll
        for (int c = 0; c < 4; ++c)
            bfr[c] = *(const frag_ab*)&Bls[wn * 64 + c * 16 + mr][quad * 8];
#pragma unroll
        for (int r = 0; r < 4; ++r)
#pragma unroll
            for (int c = 0; c < 4; ++c)
                acc[r][c] = __builtin_amdgcn_mfma_f32_16x16x32_bf16(af[r], bfr[c], acc[r][c], 0, 0, 0);
    }

    bool f32m = (MODE == 1) ? (*flag != 0) : false;
#pragma unroll
    for (int r = 0; r < 4; ++r) {
#pragma unroll
        for (int c = 0; c < 4; ++c) {
#pragma unroll
            for (int reg = 0; reg < 4; ++reg) {
                int gm = m0 + wm * 64 + r * 16 + quad * 4 + reg;
                int gn = n0 + wn * 64 + c * 16 + mr;
                float v = acc[r][c][reg];
                if (MODE == 0) {
                    C[(size_t)gm * ldc + cofs + gn] = f2b(v);
                } else if (MODE == 2) {
                    if (gn < DTRANK + 2 * DSTATE) Cf[(size_t)gm * 56 + gn] = v;
                } else if (MODE == 3) {  // ydir *= silu(z),  v == z
                    size_t idx = (size_t)gm * ldc + cofs + gn;
                    float y = b2f(C[idx]);
                    float sz = v / (1.f + __expf(-v));
                    C[idx] = f2b(y * sz);
                } else {  // gate: g*yf + (1-g)*yb + x  (A == ycat)
                    float g   = 1.f / (1.f + __expf(-(v + gb[gn])));
                    float yfv = b2f(A[(size_t)gm * DINNER + gn]);
                    float ybv = b2f(A[(size_t)gm * DINNER + DMODEL + gn]);
                    size_t gi = xoff + (size_t)gm * DMODEL + gn;
                    float xv  = f32m ? ((const float*)xg)[gi] : b2f(((const bf16*)xg)[gi]);
                    float rr  = g * yfv + (1.f - g) * ybv + xv;
                    if (f32m) ((float*)outg)[gi] = rr;
                    else      ((bf16*)outg)[gi]  = f2b(rr);
                }
            }
        }
    }
}

// ------------------------------------------------------------------
// Depthwise conv (causal fwd / anti-causal reversed-tap bwd) + SiLU, bf16.
// ------------------------------------------------------------------
__global__ void conv_kernel(const bf16* __restrict__ xi_buf, const float* __restrict__ cw,
                            const float* __restrict__ cb, bf16* __restrict__ xc, int reverse) {
    int g = blockIdx.x * blockDim.x + threadIdx.x;
    int c  = g % DINNER;
    int bl = g / DINNER;
    int l = bl % SEQ;
    int b = bl / SEQ;
    float w[4];
#pragma unroll
    for (int k = 0; k < 4; ++k) w[k] = cw[c * 4 + k];
    const bf16* xi = xi_buf + (size_t)b * SEQ * DINNER + c;
    float acc = cb[c];
    if (!reverse) {
#pragma unroll
        for (int k = 0; k < 4; ++k) {
            int ll = l - 3 + k;
            if (ll >= 0) acc += b2f(xi[(size_t)ll * DINNER]) * w[k];
        }
    } else {
#pragma unroll
        for (int j = 0; j < 4; ++j) {
            int ll = l + j;
            if (ll < SEQ) acc += b2f(xi[(size_t)ll * DINNER]) * w[3 - j];
        }
    }
    xc[(size_t)bl * DINNER + c] = f2b(acc / (1.f + __expf(-acc)));
}

// ------------------------------------------------------------------
// dt precompute: dt[row,c] = softplus(dtb[c] + sum_r xp[row,r]*dtw[c,r]).
// Token-parallel; removes the 24-FMA projection + softplus from the scan.
// ------------------------------------------------------------------
__global__ void dt_kernel(const float* __restrict__ xp, const float* __restrict__ dtw,
                          const float* __restrict__ dtb, float* __restrict__ dtf) {
    int g = blockIdx.x * 256 + threadIdx.x;
    int c   = g % DINNER;
    int row = g / DINNER;
    const float* xr = xp + (size_t)row * 56;
    float dt = dtb[c];
#pragma unroll
    for (int r = 0; r < DTRANK; ++r) dt += xr[r] * dtw[c * DTRANK + r];
    dt = fmaxf(dt, 0.f) + log1pf(__expf(-fabsf(dt)));  // softplus
    dtf[(size_t)row * DINNER + c] = dt;
}

// ------------------------------------------------------------------
// Chunked selective scan over TC chunks of CL steps.
// PHASE 0: from h=0: P = prod dA, h_end -> states.  (structured: P=Q^(n+1))
// stitch : serial compose; stores h_in into the P slot.
// PHASE 1: from h_in, emit y = C.h + D*xc  (silu(z) applied later by MODE-3).
// Structured A path (flag[1]==0): dA[n] = e1^(n+1), e1 = exp(dt*Av0):
// 1 transcendental per step instead of 16.
// ------------------------------------------------------------------
template <int PHASE>
__global__ void scan_phase(const float* __restrict__ xp, const bf16* __restrict__ xc,
                           const float* __restrict__ dtf, const float* __restrict__ Alog,
                           const float* __restrict__ Dg, float* __restrict__ states,
                           bf16* __restrict__ ydir, int reverse, const int* __restrict__ flag) {
    __shared__ float xps[16][32];
    bool generic = (flag[1] != 0);
    int tid = threadIdx.x;
    int bidx = blockIdx.x;
    int tc  = bidx % TC;
    int cgb = bidx / TC;       // bb*6+cg
    int cg  = cgb % 6;
    int bb  = cgb / 6;
    int c = cg * 128 + tid;

    float Av0 = -__expf(Alog[c * DSTATE]);
    float Av[DSTATE];
    if (generic) {
#pragma unroll
        for (int n = 0; n < DSTATE; ++n) Av[n] = -__expf(Alog[c * DSTATE + n]);
    }
    float Dv = Dg[c];

    float h[DSTATE];
    float Q = 1.f, Pg[DSTATE];
    size_t sbase = (size_t)bidx * 32;
    if (PHASE == 0) {
#pragma unroll
        for (int n = 0; n < DSTATE; ++n) { h[n] = 0.f; Pg[n] = 1.f; }
    } else {
#pragma unroll
        for (int n = 0; n < DSTATE; ++n) h[n] = states[(sbase + n) * 128 + tid];
    }

    const size_t brow = (size_t)bb * SEQ;
    for (int g0 = tc * CL; g0 < tc * CL + CL; g0 += 16) {
        __syncthreads();
        for (int i = tid; i < 16 * 32; i += 128) {
            int s = i >> 5, r = i & 31;
            int t = g0 + s;
            int tr = reverse ? (SEQ - 1 - t) : t;
            xps[s][r] = xp[(brow + tr) * 56 + 24 + r];
        }
        __syncthreads();
        for (int s = 0; s < 16; ++s) {
            int t = g0 + s;
            int tr = reverse ? (SEQ - 1 - t) : t;
            size_t row = brow + tr;
            float dt  = dtf[row * DINNER + c];
            float xcv = b2f(xc[row * DINNER + c]);
            float dtx = dt * xcv;
            float accv = 0.f;
            if (!generic) {
                float e1 = __expf(dt * Av0);
                float d = e1;
#pragma unroll
                for (int n = 0; n < DSTATE; ++n) {
                    h[n] = d * h[n] + dtx * xps[s][n];
                    if (PHASE == 1) accv += h[n] * xps[s][16 + n];
                    d *= e1;
                }
                if (PHASE == 0) Q *= e1;
            } else {
#pragma unroll
                for (int n = 0; n < DSTATE; ++n) {
                    float dA = __expf(dt * Av[n]);
                    h[n] = dA * h[n] + dtx * xps[s][n];
                    if (PHASE == 0) Pg[n] *= dA;
                    else accv += h[n] * xps[s][16 + n];
                }
            }
            if (PHASE == 1)
                ydir[row * DINNER + c] = f2b(accv + xcv * Dv);
        }
    }
    if (PHASE == 0) {
        if (!generic) {
            float d = Q;
#pragma unroll
            for (int n = 0; n < DSTATE; ++n) { Pg[n] = d; d *= Q; }
        }
#pragma unroll
        for (int n = 0; n < DSTATE; ++n) {
            states[(sbase + n) * 128 + tid]      = Pg[n];
            states[(sbase + 16 + n) * 128 + tid] = h[n];
        }
    }
}

__global__ void scan_stitch(float* __restrict__ states) {
    int tid = threadIdx.x;
    int cgb = blockIdx.x;
    float h[DSTATE];
#pragma unroll
    for (int n = 0; n < DSTATE; ++n) h[n] = 0.f;
    for (int tc = 0; tc < TC; ++tc) {
        size_t base = ((size_t)cgb * TC + tc) * 32;
#pragma unroll
        for (int n = 0; n < DSTATE; ++n) {
            float Pv = states[(base + n) * 128 + tid];
            float ev = states[(base + 16 + n) * 128 + tid];
            states[(base + n) * 128 + tid] = h[n];   // h_in for this chunk
            h[n] = Pv * h[n] + ev;
        }
    }
}

// ------------------------------------------------------------------
extern "C" void kernel_launch(void* const* d_in, const int* in_sizes, int n_in,
                              void* d_out, int out_size, void* d_ws, size_t ws_size,
                              hipStream_t stream) {
    (void)n_in; (void)out_size;
    bool dict_order = (in_sizes[4] < 2048);
    int fbase = dict_order ? 5 : 3;
    int bbase = dict_order ? 14 : 12;
    int gwi = dict_order ? 3 : 21;
    int gbi = dict_order ? 4 : 22;

    auto al = [](size_t b) { return (b + 255) & ~(size_t)255; };
    char* ws = (char*)d_ws;
    size_t off = 0;
    auto alloc = [&](size_t bytes) {
        void* p = ws + off;
        off += al(bytes);
        return p;
    };

    int* flag = (int*)alloc(256);

    CvtF pf{};
    int cf = 0;
    auto addf = [&](int idx, int n) {
        float* d = (float*)alloc((size_t)n * 4);
        pf.src[cf] = d_in[idx]; pf.dst[cf] = d; pf.n[cf] = n; ++cf;
        return d;
    };
    float* ln_gc   = addf(1, DMODEL);
    float* ln_bc   = addf(2, DMODEL);
    float* gate_bc = addf(gbi, DMODEL);
    float* convw_f[2], *convb_f[2], *dtw_f[2], *dtb_f[2], *alog_f[2], *dd_f[2];
    for (int d = 0; d < 2; ++d) {
        int base = d ? bbase : fbase;
        convw_f[d] = addf(base + 1, DINNER * 4);
        convb_f[d] = addf(base + 2, DINNER);
        dtw_f[d]   = addf(base + 4, DINNER * DTRANK);
        dtb_f[d]   = addf(base + 5, DINNER);
        alog_f[d]  = addf(base + 6, DINNER * DSTATE);
        dd_f[d]    = addf(base + 7, DINNER);
    }

    CvtB pb{};
    int cb = 0;
    auto addb = [&](int idx, int n, size_t alloc_n) {
        bf16* d = (bf16*)alloc(alloc_n * 2);
        pb.src[cb] = d_in[idx]; pb.dst[cb] = d; pb.n[cb] = n; ++cb;
        return d;
    };
    bf16* gate_wb = addb(gwi, DMODEL * 2 * DMODEL, (size_t)DMODEL * 2 * DMODEL);
    bf16 *inw_b[2], *xpw_b[2], *outw_b[2];
    for (int d = 0; d < 2; ++d) {
        int base = d ? bbase : fbase;
        inw_b[d]  = addb(base + 0, 2 * DINNER * DMODEL, (size_t)2 * DINNER * DMODEL);
        xpw_b[d]  = addb(base + 3, 56 * DINNER, (size_t)128 * DINNER);  // padded
        outw_b[d] = addb(base + 8, DMODEL * DINNER, (size_t)DMODEL * DINNER);
    }
    size_t fixed = off;

    // per-chunk activations (zb eliminated; dt f32 added; states at TC=32)
    auto chunk_need = [&](int bc) {
        size_t T = (size_t)bc * SEQ;
        return al(T * DMODEL * 2)                       // xn
             + 2 * al(T * DINNER * 2)                   // xi(/ydir), xc
             + al(T * 56 * 4)                           // xp f32
             + al(T * DINNER * 4)                       // dt f32
             + al(T * DINNER * 2)                       // ycat
             + al((size_t)bc * 6 * TC * 32 * 128 * 4);  // scan states
    };
    int Bc = 32;
    while (Bc > 1 && fixed + chunk_need(Bc) > ws_size) Bc >>= 1;
    size_t T = (size_t)Bc * SEQ;

    bf16*  xn_c   = (bf16*)alloc(T * DMODEL * 2);
    bf16*  xib    = (bf16*)alloc(T * DINNER * 2);
    bf16*  xcb    = (bf16*)alloc(T * DINNER * 2);
    float* xpb    = (float*)alloc(T * 56 * 4);
    float* dtfb   = (float*)alloc(T * DINNER * 4);
    bf16*  ycat   = (bf16*)alloc(T * DINNER * 2);
    float* states = (float*)alloc((size_t)Bc * 6 * TC * 32 * 128 * 4);
    bf16*  ydir   = xib;  // alias: xi dead after conv

    hipMemsetAsync(flag, 0, 8, stream);
    for (int d = 0; d < 2; ++d)
        hipMemsetAsync(xpw_b[d], 0, (size_t)128 * DINNER * 2, stream);
    detect_kernel<<<1, 256, 0, stream>>>((const unsigned short*)d_in[0], flag);
    convert_f_kernel<<<dim3(8, 15), 256, 0, stream>>>(pf, flag);
    convert_b_kernel<<<dim3(32, 7), 256, 0, stream>>>(pb, flag);
    struct_check<<<3, 256, 0, stream>>>(alog_f[0], flag);
    struct_check<<<3, 256, 0, stream>>>(alog_f[1], flag);

    for (int c0 = 0; c0 < BATCH; c0 += Bc) {
        size_t tok0 = (size_t)c0 * SEQ;

        ln_kernel<<<(unsigned)(T / 4), 256, 0, stream>>>(
            d_in[0], tok0 * DMODEL, ln_gc, ln_bc, xn_c, flag);

        for (int dir = 0; dir < 2; ++dir) {
            // in-proj xi half
            gemm_mfma<0><<<dim3(DINNER / 128, T / 128), 256, 0, stream>>>(
                xn_c, inw_b[dir], DMODEL, DMODEL, DMODEL,
                xib, DINNER, 0, nullptr, nullptr, nullptr, 0, nullptr, flag);
            conv_kernel<<<(unsigned)((T * DINNER) / 256), 256, 0, stream>>>(
                xib, convw_f[dir], convb_f[dir], xcb, dir);
            // x-proj (56 cols padded to 128)
            gemm_mfma<2><<<dim3(1, T / 128), 256, 0, stream>>>(
                xcb, xpw_b[dir], DINNER, DINNER, DINNER,
                nullptr, 0, 0, xpb, nullptr, nullptr, 0, nullptr, flag);
            dt_kernel<<<(unsigned)((T * DINNER) / 256), 256, 0, stream>>>(
                xpb, dtw_f[dir], dtb_f[dir], dtfb);
            // chunked scan
            scan_phase<0><<<Bc * 6 * TC, 128, 0, stream>>>(
                xpb, xcb, dtfb, alog_f[dir], dd_f[dir], states, nullptr, dir, flag);
            scan_stitch<<<Bc * 6, 128, 0, stream>>>(states);
            scan_phase<1><<<Bc * 6 * TC, 128, 0, stream>>>(
                xpb, xcb, dtfb, alog_f[dir], dd_f[dir], states, ydir, dir, flag);
            // z in-proj GEMM with fused gating: ydir *= silu(z)
            gemm_mfma<3><<<dim3(DINNER / 128, T / 128), 256, 0, stream>>>(
                xn_c, inw_b[dir] + (size_t)DINNER * DMODEL, DMODEL, DMODEL, DMODEL,
                ydir, DINNER, 0, nullptr, nullptr, nullptr, 0, nullptr, flag);
            // out-proj into ycat columns [dir*384, dir*384+384)
            gemm_mfma<0><<<dim3(DMODEL / 128, T / 128), 256, 0, stream>>>(
                ydir, outw_b[dir], DINNER, DINNER, DINNER,
                ycat, DINNER, dir * DMODEL, nullptr, nullptr, nullptr, 0, nullptr, flag);
        }

        // gate GEMM + combine + residual
        gemm_mfma<1><<<dim3(DMODEL / 128, T / 128), 256, 0, stream>>>(
            ycat, gate_wb, DINNER, DINNER, DINNER,
            nullptr, 0, 0, nullptr, gate_bc, d_in[0], tok0 * DMODEL, d_out, flag);
    }
}